// Round 1
// 700.556 us; speedup vs baseline: 1.0125x; 1.0125x over previous
//
#include <hip/hip_runtime.h>
#include <hip/hip_bf16.h>
#include <cstdint>

#define NE   8
#define TOPK 2
#define NT   8192          // tokens
#define TK   16384         // tokens * topk
#define HS   1024
#define FFN  4096
#define CAP  2048          // expert capacity

typedef float  f32x4  __attribute__((ext_vector_type(4)));
typedef __bf16 bf16x8 __attribute__((ext_vector_type(8)));
typedef __bf16 bf16x4 __attribute__((ext_vector_type(4)));

// ---------------- async global->LDS (16B per lane) ----------------
__device__ __forceinline__ void gload_lds16(const void* g, void* l) {
  __builtin_amdgcn_global_load_lds(
      (__attribute__((address_space(1))) void*)(void*)g,
      (__attribute__((address_space(3))) void*)l,
      16, 0, 0);
}

// ---------------- routing: stable counting sort ranks ----------------
__global__ __launch_bounds__(1024)
void route_kernel(const int* __restrict__ te,
                  const float* __restrict__ ew,
                  int* __restrict__ asg_p,
                  float* __restrict__ asg_w,
                  int* __restrict__ slot_token) {
  const int e    = blockIdx.x;
  const int tid  = threadIdx.x;
  const int lane = tid & 63;
  const int w    = tid >> 6;
  __shared__ int wtot[16];
  int running = 0;
  for (int base = 0; base < TK; base += 1024) {
    const int i = base + tid;
    const int flag = (te[i] == e) ? 1 : 0;
    int val = flag;                       // inclusive wave scan
    #pragma unroll
    for (int off = 1; off < 64; off <<= 1) {
      int n = __shfl_up(val, off);
      if (lane >= off) val += n;
    }
    if (lane == 63) wtot[w] = val;
    __syncthreads();
    int woff = 0, total = 0;
    #pragma unroll
    for (int j = 0; j < 16; j++) {
      const int t = wtot[j];
      if (j < w) woff += t;
      total += t;
    }
    if (flag) {
      const int p = running + woff + val - 1;   // exclusive rank
      asg_p[i] = p;
      const bool valid = (p < CAP);
      asg_w[i] = valid ? ew[i] : 0.0f;
      if (valid) slot_token[e * CAP + p] = i >> 1;  // i / TOPK
    }
    running += total;
    __syncthreads();
  }
}

// ---------------- gather + cast to bf16 ----------------
__global__ void gather_kernel(const float* __restrict__ x,
                              const int* __restrict__ slot_token,
                              __bf16* __restrict__ Xg) {
  const int s   = blockIdx.x;
  const int tok = slot_token[s];
  const int idx = threadIdx.x * 4;
  bf16x4 o;
  if (tok >= 0) {
    const float4 v = *(const float4*)&x[(size_t)tok * HS + idx];
    o[0] = (__bf16)v.x; o[1] = (__bf16)v.y; o[2] = (__bf16)v.z; o[3] = (__bf16)v.w;
  } else {
    o[0] = (__bf16)0.f; o[1] = (__bf16)0.f; o[2] = (__bf16)0.f; o[3] = (__bf16)0.f;
  }
  *(bf16x4*)&Xg[(size_t)s * HS + idx] = o;
}

// ---------------- transpose + cast: [R][C] f32 -> [C][R] bf16 per expert ----
template<int R, int C>
__global__ void transpose_cast_kernel(const float* __restrict__ in,
                                      __bf16* __restrict__ out) {
  const int e = blockIdx.z;
  const float* in_e  = in  + (size_t)e * R * C;
  __bf16*      out_e = out + (size_t)e * R * C;
  const int c0 = blockIdx.x * 64;
  const int r0 = blockIdx.y * 64;
  __shared__ float tile[64][65];
  const int tid = threadIdx.x;
  const int lc = tid & 15, tr = tid >> 4;
  #pragma unroll
  for (int rr = 0; rr < 4; rr++) {
    const int row = rr * 16 + tr;
    const float4 v = *(const float4*)&in_e[(size_t)(r0 + row) * C + c0 + lc * 4];
    tile[row][lc * 4 + 0] = v.x; tile[row][lc * 4 + 1] = v.y;
    tile[row][lc * 4 + 2] = v.z; tile[row][lc * 4 + 3] = v.w;
  }
  __syncthreads();
  const int cb = tid & 7;
  #pragma unroll
  for (int p = 0; p < 2; p++) {
    const int orow = p * 32 + (tid >> 3);
    bf16x8 o;
    #pragma unroll
    for (int j = 0; j < 8; j++) o[j] = (__bf16)tile[cb * 8 + j][orow];
    *(bf16x8*)&out_e[(size_t)(c0 + orow) * R + r0 + cb * 8] = o;
  }
}

// ---------------- gelu (tanh approx, matches jax.nn.gelu) ----------------
__device__ __forceinline__ float gelu_tanh(float v) {
  const float u = 0.7978845608028654f * (v + 0.044715f * v * v * v);
  const float t = 1.0f - 2.0f / (__expf(2.0f * u) + 1.0f);
  return 0.5f * v * (1.0f + t);
}

// ---------------- grouped GEMM: 256x256 tile, BK=32, 3-deep LDS ring ------
// A: [NE*CAP][K] bf16 row-major, B: [NE][N][K] bf16 (B^T), C: [NE*CAP][N] bf16
// 512 threads = 8 waves (2M x 4N), per-wave output 128x64 (8x4 16x16 frags).
// Schedule per K-tile (BK=32): 2 phases of
//   { ds_read frags | issue 2 global_load_lds for tile t+2 | barrier |
//     lgkmcnt(0) | setprio(1) | 16 MFMA | setprio(0) | barrier }
// then boundary: s_waitcnt vmcnt(4) (counted - never 0 in steady state) +
// barrier. Ring of 3 K-tile buffers: tile t+2 stages into (t+2)%3, which was
// freed by the *previous* boundary barrier -> no overwrite-while-read race.
// T2 swizzle: 16B slot ^= (row>>1)&3 applied on the READ address and as the
// inverse permutation of the global SOURCE column during staging (LDS dest
// stays linear, as global_load_lds requires).
template<int DO_GELU, int MT_, int NT_>
__global__ __launch_bounds__(512, 2)
void gemm256_kernel(const __bf16* __restrict__ A,
                    const __bf16* __restrict__ B,
                    __bf16* __restrict__ C,
                    int N, int K) {
  const int bid = blockIdx.x;
  const int e   = bid & 7;          // expert -> XCD pinning
  const int g   = bid >> 3;
  const int s   = g >> 4;           // 4x4 super-tiles for L2 locality
  const int r   = g & 15;
  const int sm  = s % (MT_ / 4);
  const int sn  = s / (MT_ / 4);
  const int m0  = (sm * 4 + (r >> 2)) * 256;
  const int n0  = (sn * 4 + (r & 3)) * 256;

  const int tid  = threadIdx.x;
  const int lane = tid & 63;
  const int w    = tid >> 6;        // 0..7
  const int wm   = w >> 2;          // 0..1
  const int wn   = w & 3;           // 0..3

  __shared__ __align__(16) __bf16 ldsA[3][256 * 32];   // 3 x 16 KB
  __shared__ __align__(16) __bf16 ldsB[3][256 * 32];   // 3 x 16 KB

  const size_t Abase = ((size_t)e * CAP + m0) * (size_t)K;
  const size_t Bbase = (size_t)e * N * (size_t)K + (size_t)n0 * K;

  // ---- staging addressing (per lane) ----
  // issue j covers rows [j*128, j*128+128); wave w covers 16 rows of it.
  // LDS dest is linear (wave-uniform base + lane*16); source column carries
  // the inverse swizzle: 16B chunk = (lane&3) ^ ((lane>>3)&3).
  const int srow = w * 16 + (lane >> 2);
  const int scb  = (((lane & 3) ^ ((lane >> 3) & 3)) << 3);  // elems
  const __bf16* gA = A + Abase + (size_t)srow * K + scb;
  const __bf16* gB = B + Bbase + (size_t)srow * K + scb;
  const int ldst = w * 512;   // wave-uniform elem offset within an 8KB issue

  // ---- read addressing (per lane), element offsets, swizzled ----
  const int rA0  = wm * 128 + (lane & 15);
  const int rB0  = wn * 64  + (lane & 15);
  const int aoff = rA0 * 32 + ((((lane >> 4) ^ ((rA0 >> 1) & 3))) << 3);
  const int boff = rB0 * 32 + ((((lane >> 4) ^ ((rB0 >> 1) & 3))) << 3);

  f32x4 acc[8][4] = {};

  const int NKT = K >> 5;   // K-tiles of 32

#define STAGE_A(buf, kt) do {                                             \
    const __bf16* _g = gA + (size_t)(kt) * 32;                            \
    gload_lds16(_g,                    &ldsA[buf][ldst]);                 \
    gload_lds16(_g + (size_t)128 * K,  &ldsA[buf][4096 + ldst]);          \
  } while (0)
#define STAGE_B(buf, kt) do {                                             \
    const __bf16* _g = gB + (size_t)(kt) * 32;                            \
    gload_lds16(_g,                    &ldsB[buf][ldst]);                 \
    gload_lds16(_g + (size_t)128 * K,  &ldsB[buf][4096 + ldst]);          \
  } while (0)

  // prologue: stage K-tiles 0 and 1 (8 vmem issues); wait so tile 0 landed.
  STAGE_A(0, 0); STAGE_B(0, 0);
  STAGE_A(1, 1); STAGE_B(1, 1);
  asm volatile("s_waitcnt vmcnt(4)" ::: "memory");
  __builtin_amdgcn_s_barrier();
  asm volatile("" ::: "memory");

  int cur = 0, stg = 2;
  for (int t = 0; t < NKT; ++t) {
    const bool do_stage = (t + 2 < NKT);
    bf16x8 aq[4], bq[4];

    // ---- phase 0: B frags (full BK) + A frags rows 0..63, MFMA acc[0..3] --
    #pragma unroll
    for (int i = 0; i < 4; ++i) bq[i] = *(const bf16x8*)&ldsB[cur][boff + i * 512];
    #pragma unroll
    for (int i = 0; i < 4; ++i) aq[i] = *(const bf16x8*)&ldsA[cur][aoff + i * 512];
    if (do_stage) STAGE_A(stg, t + 2);
    __builtin_amdgcn_s_barrier();
    asm volatile("s_waitcnt lgkmcnt(0)" ::: "memory");
    __builtin_amdgcn_s_setprio(1);
    #pragma unroll
    for (int mi = 0; mi < 4; ++mi)
      #pragma unroll
      for (int ni = 0; ni < 4; ++ni)
        acc[mi][ni] = __builtin_amdgcn_mfma_f32_16x16x32_bf16(aq[mi], bq[ni], acc[mi][ni], 0, 0, 0);
    __builtin_amdgcn_s_setprio(0);
    __builtin_amdgcn_s_barrier();
    asm volatile("" ::: "memory");

    // ---- phase 1: A frags rows 64..127 (reuse bq), MFMA acc[4..7] ----
    #pragma unroll
    for (int i = 0; i < 4; ++i) aq[i] = *(const bf16x8*)&ldsA[cur][aoff + 2048 + i * 512];
    if (do_stage) STAGE_B(stg, t + 2);
    __builtin_amdgcn_s_barrier();
    asm volatile("s_waitcnt lgkmcnt(0)" ::: "memory");
    __builtin_amdgcn_s_setprio(1);
    #pragma unroll
    for (int mi = 0; mi < 4; ++mi)
      #pragma unroll
      for (int ni = 0; ni < 4; ++ni)
        acc[4 + mi][ni] = __builtin_amdgcn_mfma_f32_16x16x32_bf16(aq[mi], bq[ni], acc[4 + mi][ni], 0, 0, 0);
    __builtin_amdgcn_s_setprio(0);

    // ---- K-tile boundary: counted wait (tile t+1 landed), one barrier ----
    if (t + 1 < NKT) {
      if (do_stage) { asm volatile("s_waitcnt vmcnt(4)" ::: "memory"); }
      else          { asm volatile("s_waitcnt vmcnt(0)" ::: "memory"); }
      __builtin_amdgcn_s_barrier();
      asm volatile("" ::: "memory");
    }
    cur = (cur == 2) ? 0 : cur + 1;
    stg = (stg == 2) ? 0 : stg + 1;
  }
#undef STAGE_A
#undef STAGE_B

  // ---- epilogue: D row=(lane>>4)*4+rr (m), col=lane&15 (n) ----
  const int crow = (lane >> 4) * 4;
  const int ccol = lane & 15;
  const size_t Crow0 = (size_t)e * CAP + m0 + wm * 128;
  #pragma unroll
  for (int mi = 0; mi < 8; ++mi) {
    #pragma unroll
    for (int ni = 0; ni < 4; ++ni) {
      const f32x4 d = acc[mi][ni];
      const int col = n0 + wn * 64 + ni * 16 + ccol;
      #pragma unroll
      for (int rr = 0; rr < 4; ++rr) {
        float v = d[rr];
        if (DO_GELU) v = gelu_tanh(v);
        C[(Crow0 + mi * 16 + crow + rr) * (size_t)N + col] = (__bf16)v;
      }
    }
  }
}

// ---------------- combine: y = bias + sum_k w * Out[slot] ----------------
__global__ void combine_kernel(const __bf16* __restrict__ Out,
                               const int* __restrict__ te,
                               const int* __restrict__ asg_p,
                               const float* __restrict__ asg_w,
                               const float* __restrict__ bias,
                               float* __restrict__ y) {
  const int t   = blockIdx.x;
  const int idx = threadIdx.x * 4;
  f32x4 acc = *(const f32x4*)&bias[idx];
  #pragma unroll
  for (int j = 0; j < TOPK; j++) {
    const int i = t * TOPK + j;
    const float wgt = asg_w[i];
    if (wgt != 0.0f) {
      const int slot = te[i] * CAP + asg_p[i];
      const bf16x4 o = *(const bf16x4*)&Out[(size_t)slot * HS + idx];
      acc[0] += wgt * (float)o[0];
      acc[1] += wgt * (float)o[1];
      acc[2] += wgt * (float)o[2];
      acc[3] += wgt * (float)o[3];
    }
  }
  *(f32x4*)&y[(size_t)t * HS + idx] = acc;
}

// ---------------- workspace layout (bytes) ----------------
static constexpr size_t OFF_SLOT = 0;                          //  64 KB int
static constexpr size_t OFF_ASGP = 65536;                      //  64 KB int
static constexpr size_t OFF_ASGW = 131072;                     //  64 KB f32
static constexpr size_t OFF_XG   = 196608;                     //  32 MB bf16 [NE*CAP][HS]
static constexpr size_t OFF_W1T  = OFF_XG  + (size_t)TK * HS * 2;        // 64 MB bf16 [NE][FFN][HS]
static constexpr size_t OFF_W2T  = OFF_W1T + (size_t)NE * HS * FFN * 2;  // 64 MB bf16 [NE][HS][FFN]
static constexpr size_t OFF_H    = OFF_W2T + (size_t)NE * HS * FFN * 2;  // 128 MB bf16 [NE*CAP][FFN]
static constexpr size_t OFF_OUT  = OFF_H   + (size_t)NE * CAP * FFN * 2; // 32 MB bf16 [NE*CAP][HS]

extern "C" void kernel_launch(void* const* d_in, const int* in_sizes, int n_in,
                              void* d_out, int out_size, void* d_ws, size_t ws_size,
                              hipStream_t stream) {
  const float* x    = (const float*)d_in[0];
  const float* ew   = (const float*)d_in[1];
  const float* w1   = (const float*)d_in[2];
  const float* w2   = (const float*)d_in[3];
  const float* bias = (const float*)d_in[4];
  const int*   te   = (const int*)d_in[5];
  float* y = (float*)d_out;

  char* ws = (char*)d_ws;
  int*    slot_token = (int*)(ws + OFF_SLOT);
  int*    asg_p      = (int*)(ws + OFF_ASGP);
  float*  asg_w      = (float*)(ws + OFF_ASGW);
  __bf16* Xg         = (__bf16*)(ws + OFF_XG);
  __bf16* W1t        = (__bf16*)(ws + OFF_W1T);
  __bf16* W2t        = (__bf16*)(ws + OFF_W2T);
  __bf16* H          = (__bf16*)(ws + OFF_H);
  __bf16* Out        = (__bf16*)(ws + OFF_OUT);

  // 1. slot_token = -1
  hipMemsetAsync(slot_token, 0xFF, (size_t)NE * CAP * sizeof(int), stream);

  // 2. routing (stable ranks)
  route_kernel<<<NE, 1024, 0, stream>>>(te, ew, asg_p, asg_w, slot_token);

  // 3. weight transpose+cast
  transpose_cast_kernel<HS, FFN><<<dim3(FFN / 64, HS / 64, NE), 256, 0, stream>>>(w1, W1t);
  transpose_cast_kernel<FFN, HS><<<dim3(HS / 64, FFN / 64, NE), 256, 0, stream>>>(w2, W2t);

  // 4. gather tokens into expert bins (bf16)
  gather_kernel<<<NE * CAP, 256, 0, stream>>>(x, slot_token, Xg);

  // 5. H = gelu(Xg @ w1)   (M=CAP, N=FFN, K=HS)   8 m-tiles, 16 n-tiles
  gemm256_kernel<1, 8, 16><<<NE * 8 * 16, 512, 0, stream>>>(Xg, W1t, H, FFN, HS);

  // 6. Out = H @ w2        (M=CAP, N=HS, K=FFN)   8 m-tiles, 4 n-tiles
  gemm256_kernel<0, 8, 4><<<NE * 8 * 4, 512, 0, stream>>>(H, W2t, Out, HS, FFN);

  // 7. combine back to tokens
  combine_kernel<<<NT, 256, 0, stream>>>(Out, te, asg_p, asg_w, bias, y);
}

// Round 2
// 688.338 us; speedup vs baseline: 1.0305x; 1.0178x over previous
//
#include <hip/hip_runtime.h>
#include <hip/hip_bf16.h>
#include <cstdint>

#define NE   8
#define TOPK 2
#define NT   8192          // tokens
#define TK   16384         // tokens * topk
#define HS   1024
#define FFN  4096
#define CAP  2048          // expert capacity

typedef float  f32x4  __attribute__((ext_vector_type(4)));
typedef __bf16 bf16x8 __attribute__((ext_vector_type(8)));
typedef __bf16 bf16x4 __attribute__((ext_vector_type(4)));

// ---------------- async global->LDS (16B per lane) ----------------
__device__ __forceinline__ void gload_lds16(const void* g, void* l) {
  __builtin_amdgcn_global_load_lds(
      (__attribute__((address_space(1))) void*)(void*)g,
      (__attribute__((address_space(3))) void*)l,
      16, 0, 0);
}

// ---------------- routing: stable counting sort ranks ----------------
__global__ __launch_bounds__(1024)
void route_kernel(const int* __restrict__ te,
                  const float* __restrict__ ew,
                  int* __restrict__ asg_p,
                  float* __restrict__ asg_w,
                  int* __restrict__ slot_token) {
  const int e    = blockIdx.x;
  const int tid  = threadIdx.x;
  const int lane = tid & 63;
  const int w    = tid >> 6;
  __shared__ int wtot[16];
  int running = 0;
  for (int base = 0; base < TK; base += 1024) {
    const int i = base + tid;
    const int flag = (te[i] == e) ? 1 : 0;
    int val = flag;                       // inclusive wave scan
    #pragma unroll
    for (int off = 1; off < 64; off <<= 1) {
      int n = __shfl_up(val, off);
      if (lane >= off) val += n;
    }
    if (lane == 63) wtot[w] = val;
    __syncthreads();
    int woff = 0, total = 0;
    #pragma unroll
    for (int j = 0; j < 16; j++) {
      const int t = wtot[j];
      if (j < w) woff += t;
      total += t;
    }
    if (flag) {
      const int p = running + woff + val - 1;   // exclusive rank
      asg_p[i] = p;
      const bool valid = (p < CAP);
      asg_w[i] = valid ? ew[i] : 0.0f;
      if (valid) slot_token[e * CAP + p] = i >> 1;  // i / TOPK
    }
    running += total;
    __syncthreads();
  }
}

// ---------------- gather + cast to bf16 ----------------
__global__ void gather_kernel(const float* __restrict__ x,
                              const int* __restrict__ slot_token,
                              __bf16* __restrict__ Xg) {
  const int s   = blockIdx.x;
  const int tok = slot_token[s];
  const int idx = threadIdx.x * 4;
  bf16x4 o;
  if (tok >= 0) {
    const float4 v = *(const float4*)&x[(size_t)tok * HS + idx];
    o[0] = (__bf16)v.x; o[1] = (__bf16)v.y; o[2] = (__bf16)v.z; o[3] = (__bf16)v.w;
  } else {
    o[0] = (__bf16)0.f; o[1] = (__bf16)0.f; o[2] = (__bf16)0.f; o[3] = (__bf16)0.f;
  }
  *(bf16x4*)&Xg[(size_t)s * HS + idx] = o;
}

// ---------------- transpose + cast: [R][C] f32 -> [C][R] bf16 per expert ----
template<int R, int C>
__global__ void transpose_cast_kernel(const float* __restrict__ in,
                                      __bf16* __restrict__ out) {
  const int e = blockIdx.z;
  const float* in_e  = in  + (size_t)e * R * C;
  __bf16*      out_e = out + (size_t)e * R * C;
  const int c0 = blockIdx.x * 64;
  const int r0 = blockIdx.y * 64;
  __shared__ float tile[64][65];
  const int tid = threadIdx.x;
  const int lc = tid & 15, tr = tid >> 4;
  #pragma unroll
  for (int rr = 0; rr < 4; rr++) {
    const int row = rr * 16 + tr;
    const float4 v = *(const float4*)&in_e[(size_t)(r0 + row) * C + c0 + lc * 4];
    tile[row][lc * 4 + 0] = v.x; tile[row][lc * 4 + 1] = v.y;
    tile[row][lc * 4 + 2] = v.z; tile[row][lc * 4 + 3] = v.w;
  }
  __syncthreads();
  const int cb = tid & 7;
  #pragma unroll
  for (int p = 0; p < 2; p++) {
    const int orow = p * 32 + (tid >> 3);
    bf16x8 o;
    #pragma unroll
    for (int j = 0; j < 8; j++) o[j] = (__bf16)tile[cb * 8 + j][orow];
    *(bf16x8*)&out_e[(size_t)(c0 + orow) * R + r0 + cb * 8] = o;
  }
}

// ---------------- gelu (tanh approx, matches jax.nn.gelu) ----------------
__device__ __forceinline__ float gelu_tanh(float v) {
  const float u = 0.7978845608028654f * (v + 0.044715f * v * v * v);
  const float t = 1.0f - 2.0f / (__expf(2.0f * u) + 1.0f);
  return 0.5f * v * (1.0f + t);
}

// ---------------- grouped GEMM: 256x256 tile, BK=32, 3-ring, 1 barrier ----
// A: [NE*CAP][K] bf16 row-major, B: [NE][N][K] bf16 (B^T), C: [NE*CAP][N] bf16
// 512 threads = 8 waves (2M x 4N), per-wave output 128x64 (8x4 16x16 frags).
// Per K-tile (BK=32):
//   s_waitcnt vmcnt(4)   (counted: tile t's staging, issued 2 iters ago,
//                         is the oldest-beyond-4 -> guaranteed retired;
//                         never drains to 0 in steady state)
//   s_barrier            (now ALL waves' staging of buf cur is visible,
//                         and all waves' reads of buf stg are complete)
//   12 x ds_read_b128 (frags) | issue 4 global_load_lds for tile t+2
//   setprio(1) 32 x MFMA setprio(0)
// ONE barrier per tile -> waves slip inside the tile window, so one wave's
// LDS-read service overlaps another's MFMA section (the round-1 per-phase
// barriers serialized these and capped MfmaUtil at ~28%).
// No inline lgkmcnt: compiler inserts fine-grained waits for ds_read->MFMA.
// T2 swizzle (verified round 1: SQ_LDS_BANK_CONFLICT == 0): 16B slot index
// ^= (row>>1)&3, applied on the read address and as the inverse permutation
// of the global SOURCE column during staging (LDS dest stays linear, as
// global_load_lds requires).
template<int DO_GELU, int MT_, int NT_>
__global__ __launch_bounds__(512, 2)
void gemm256_kernel(const __bf16* __restrict__ A,
                    const __bf16* __restrict__ B,
                    __bf16* __restrict__ C,
                    int N, int K) {
  const int bid = blockIdx.x;
  const int e   = bid & 7;          // expert -> XCD pinning
  const int g   = bid >> 3;
  const int s   = g >> 4;           // 4x4 super-tiles for L2 locality
  const int r   = g & 15;
  const int sm  = s % (MT_ / 4);
  const int sn  = s / (MT_ / 4);
  const int m0  = (sm * 4 + (r >> 2)) * 256;
  const int n0  = (sn * 4 + (r & 3)) * 256;

  const int tid  = threadIdx.x;
  const int lane = tid & 63;
  const int w    = tid >> 6;        // 0..7
  const int wm   = w >> 2;          // 0..1
  const int wn   = w & 3;           // 0..3

  __shared__ __align__(16) __bf16 ldsA[3][256 * 32];   // 3 x 16 KB
  __shared__ __align__(16) __bf16 ldsB[3][256 * 32];   // 3 x 16 KB

  const size_t Abase = ((size_t)e * CAP + m0) * (size_t)K;
  const size_t Bbase = (size_t)e * N * (size_t)K + (size_t)n0 * K;

  // ---- staging addressing (per lane) ----
  // issue j covers rows [j*128, j*128+128); wave w covers 16 rows of it.
  // LDS dest is linear (wave-uniform base + lane*16); source column carries
  // the inverse swizzle: 16B chunk = (lane&3) ^ ((lane>>3)&3).
  const int srow = w * 16 + (lane >> 2);
  const int scb  = (((lane & 3) ^ ((lane >> 3) & 3)) << 3);  // elems
  const __bf16* gA = A + Abase + (size_t)srow * K + scb;
  const __bf16* gB = B + Bbase + (size_t)srow * K + scb;
  const int ldst = w * 512;   // wave-uniform elem offset within an 8KB issue

  // ---- read addressing (per lane), element offsets, swizzled ----
  const int rA0  = wm * 128 + (lane & 15);
  const int rB0  = wn * 64  + (lane & 15);
  const int aoff = rA0 * 32 + ((((lane >> 4) ^ ((rA0 >> 1) & 3))) << 3);
  const int boff = rB0 * 32 + ((((lane >> 4) ^ ((rB0 >> 1) & 3))) << 3);

  f32x4 acc[8][4] = {};

  const int NKT = K >> 5;   // K-tiles of 32

#define STAGE_A(buf, kt) do {                                             \
    const __bf16* _g = gA + (size_t)(kt) * 32;                            \
    gload_lds16(_g,                    &ldsA[buf][ldst]);                 \
    gload_lds16(_g + (size_t)128 * K,  &ldsA[buf][4096 + ldst]);          \
  } while (0)
#define STAGE_B(buf, kt) do {                                             \
    const __bf16* _g = gB + (size_t)(kt) * 32;                            \
    gload_lds16(_g,                    &ldsB[buf][ldst]);                 \
    gload_lds16(_g + (size_t)128 * K,  &ldsB[buf][4096 + ldst]);          \
  } while (0)

  // prologue: stage K-tiles 0 and 1 (8 vmem issues, 4 per tile)
  STAGE_A(0, 0); STAGE_B(0, 0);
  STAGE_A(1, 1); STAGE_B(1, 1);

  int cur = 0, stg = 2;
  for (int t = 0; t < NKT; ++t) {
    // counted wait: tile t's 4 staging issues are the oldest; with tiles
    // t+1 (4 issues) and nothing else outstanding beyond them, vmcnt(4)
    // retires exactly tile t. Last iteration has only its own 4 -> vmcnt(0).
    if (t + 1 < NKT) { asm volatile("s_waitcnt vmcnt(4)" ::: "memory"); }
    else             { asm volatile("s_waitcnt vmcnt(0)" ::: "memory"); }
    __builtin_amdgcn_s_barrier();
    asm volatile("" ::: "memory");

    // fragment reads for the whole K-tile (compiler schedules ds_read->MFMA
    // waits fine-grained; waves slip against each other inside this window)
    bf16x8 bq[4], al[4], ah[4];
    #pragma unroll
    for (int i = 0; i < 4; ++i) bq[i] = *(const bf16x8*)&ldsB[cur][boff + i * 512];
    #pragma unroll
    for (int i = 0; i < 4; ++i) al[i] = *(const bf16x8*)&ldsA[cur][aoff + i * 512];
    #pragma unroll
    for (int i = 0; i < 4; ++i) ah[i] = *(const bf16x8*)&ldsA[cur][aoff + 2048 + i * 512];

    // prefetch tile t+2 into the buffer freed at the barrier above
    if (t + 2 < NKT) { STAGE_A(stg, t + 2); STAGE_B(stg, t + 2); }

    __builtin_amdgcn_s_setprio(1);
    #pragma unroll
    for (int mi = 0; mi < 4; ++mi)
      #pragma unroll
      for (int ni = 0; ni < 4; ++ni)
        acc[mi][ni] = __builtin_amdgcn_mfma_f32_16x16x32_bf16(al[mi], bq[ni], acc[mi][ni], 0, 0, 0);
    #pragma unroll
    for (int mi = 0; mi < 4; ++mi)
      #pragma unroll
      for (int ni = 0; ni < 4; ++ni)
        acc[4 + mi][ni] = __builtin_amdgcn_mfma_f32_16x16x32_bf16(ah[mi], bq[ni], acc[4 + mi][ni], 0, 0, 0);
    __builtin_amdgcn_s_setprio(0);

    cur = (cur == 2) ? 0 : cur + 1;
    stg = (stg == 2) ? 0 : stg + 1;
  }
#undef STAGE_A
#undef STAGE_B

  // ---- epilogue: D row=(lane>>4)*4+rr (m), col=lane&15 (n) ----
  const int crow = (lane >> 4) * 4;
  const int ccol = lane & 15;
  const size_t Crow0 = (size_t)e * CAP + m0 + wm * 128;
  #pragma unroll
  for (int mi = 0; mi < 8; ++mi) {
    #pragma unroll
    for (int ni = 0; ni < 4; ++ni) {
      const f32x4 d = acc[mi][ni];
      const int col = n0 + wn * 64 + ni * 16 + ccol;
      #pragma unroll
      for (int rr = 0; rr < 4; ++rr) {
        float v = d[rr];
        if (DO_GELU) v = gelu_tanh(v);
        C[(Crow0 + mi * 16 + crow + rr) * (size_t)N + col] = (__bf16)v;
      }
    }
  }
}

// ---------------- combine: y = bias + sum_k w * Out[slot] ----------------
__global__ void combine_kernel(const __bf16* __restrict__ Out,
                               const int* __restrict__ te,
                               const int* __restrict__ asg_p,
                               const float* __restrict__ asg_w,
                               const float* __restrict__ bias,
                               float* __restrict__ y) {
  const int t   = blockIdx.x;
  const int idx = threadIdx.x * 4;
  f32x4 acc = *(const f32x4*)&bias[idx];
  #pragma unroll
  for (int j = 0; j < TOPK; j++) {
    const int i = t * TOPK + j;
    const float wgt = asg_w[i];
    if (wgt != 0.0f) {
      const int slot = te[i] * CAP + asg_p[i];
      const bf16x4 o = *(const bf16x4*)&Out[(size_t)slot * HS + idx];
      acc[0] += wgt * (float)o[0];
      acc[1] += wgt * (float)o[1];
      acc[2] += wgt * (float)o[2];
      acc[3] += wgt * (float)o[3];
    }
  }
  *(f32x4*)&y[(size_t)t * HS + idx] = acc;
}

// ---------------- workspace layout (bytes) ----------------
static constexpr size_t OFF_SLOT = 0;                          //  64 KB int
static constexpr size_t OFF_ASGP = 65536;                      //  64 KB int
static constexpr size_t OFF_ASGW = 131072;                     //  64 KB f32
static constexpr size_t OFF_XG   = 196608;                     //  32 MB bf16 [NE*CAP][HS]
static constexpr size_t OFF_W1T  = OFF_XG  + (size_t)TK * HS * 2;        // 64 MB bf16 [NE][FFN][HS]
static constexpr size_t OFF_W2T  = OFF_W1T + (size_t)NE * HS * FFN * 2;  // 64 MB bf16 [NE][HS][FFN]
static constexpr size_t OFF_H    = OFF_W2T + (size_t)NE * HS * FFN * 2;  // 128 MB bf16 [NE*CAP][FFN]
static constexpr size_t OFF_OUT  = OFF_H   + (size_t)NE * CAP * FFN * 2; // 32 MB bf16 [NE*CAP][HS]

extern "C" void kernel_launch(void* const* d_in, const int* in_sizes, int n_in,
                              void* d_out, int out_size, void* d_ws, size_t ws_size,
                              hipStream_t stream) {
  const float* x    = (const float*)d_in[0];
  const float* ew   = (const float*)d_in[1];
  const float* w1   = (const float*)d_in[2];
  const float* w2   = (const float*)d_in[3];
  const float* bias = (const float*)d_in[4];
  const int*   te   = (const int*)d_in[5];
  float* y = (float*)d_out;

  char* ws = (char*)d_ws;
  int*    slot_token = (int*)(ws + OFF_SLOT);
  int*    asg_p      = (int*)(ws + OFF_ASGP);
  float*  asg_w      = (float*)(ws + OFF_ASGW);
  __bf16* Xg         = (__bf16*)(ws + OFF_XG);
  __bf16* W1t        = (__bf16*)(ws + OFF_W1T);
  __bf16* W2t        = (__bf16*)(ws + OFF_W2T);
  __bf16* H          = (__bf16*)(ws + OFF_H);
  __bf16* Out        = (__bf16*)(ws + OFF_OUT);

  // 1. slot_token = -1
  hipMemsetAsync(slot_token, 0xFF, (size_t)NE * CAP * sizeof(int), stream);

  // 2. routing (stable ranks)
  route_kernel<<<NE, 1024, 0, stream>>>(te, ew, asg_p, asg_w, slot_token);

  // 3. weight transpose+cast
  transpose_cast_kernel<HS, FFN><<<dim3(FFN / 64, HS / 64, NE), 256, 0, stream>>>(w1, W1t);
  transpose_cast_kernel<FFN, HS><<<dim3(HS / 64, FFN / 64, NE), 256, 0, stream>>>(w2, W2t);

  // 4. gather tokens into expert bins (bf16)
  gather_kernel<<<NE * CAP, 256, 0, stream>>>(x, slot_token, Xg);

  // 5. H = gelu(Xg @ w1)   (M=CAP, N=FFN, K=HS)   8 m-tiles, 16 n-tiles
  gemm256_kernel<1, 8, 16><<<NE * 8 * 16, 512, 0, stream>>>(Xg, W1t, H, FFN, HS);

  // 6. Out = H @ w2        (M=CAP, N=HS, K=FFN)   8 m-tiles, 4 n-tiles
  gemm256_kernel<0, 8, 4><<<NE * 8 * 4, 512, 0, stream>>>(H, W2t, Out, HS, FFN);

  // 7. combine back to tokens
  combine_kernel<<<NT, 256, 0, stream>>>(Out, te, asg_p, asg_w, bias, y);
}

// Round 3
// 678.650 us; speedup vs baseline: 1.0452x; 1.0143x over previous
//
#include <hip/hip_runtime.h>
#include <hip/hip_bf16.h>
#include <cstdint>

#define NE   8
#define TOPK 2
#define NT   8192          // tokens
#define TK   16384         // tokens * topk
#define HS   1024
#define FFN  4096
#define CAP  2048          // expert capacity

typedef float  f32x4  __attribute__((ext_vector_type(4)));
typedef __bf16 bf16x8 __attribute__((ext_vector_type(8)));
typedef __bf16 bf16x4 __attribute__((ext_vector_type(4)));

// ---------------- async global->LDS (16B per lane) ----------------
__device__ __forceinline__ void gload_lds16(const void* g, void* l) {
  __builtin_amdgcn_global_load_lds(
      (__attribute__((address_space(1))) void*)(void*)g,
      (__attribute__((address_space(3))) void*)l,
      16, 0, 0);
}

// ---------------- routing: stable counting sort ranks ----------------
__global__ __launch_bounds__(1024)
void route_kernel(const int* __restrict__ te,
                  const float* __restrict__ ew,
                  int* __restrict__ asg_p,
                  float* __restrict__ asg_w,
                  int* __restrict__ slot_token) {
  const int e    = blockIdx.x;
  const int tid  = threadIdx.x;
  const int lane = tid & 63;
  const int w    = tid >> 6;
  __shared__ int wtot[16];
  int running = 0;
  for (int base = 0; base < TK; base += 1024) {
    const int i = base + tid;
    const int flag = (te[i] == e) ? 1 : 0;
    int val = flag;                       // inclusive wave scan
    #pragma unroll
    for (int off = 1; off < 64; off <<= 1) {
      int n = __shfl_up(val, off);
      if (lane >= off) val += n;
    }
    if (lane == 63) wtot[w] = val;
    __syncthreads();
    int woff = 0, total = 0;
    #pragma unroll
    for (int j = 0; j < 16; j++) {
      const int t = wtot[j];
      if (j < w) woff += t;
      total += t;
    }
    if (flag) {
      const int p = running + woff + val - 1;   // exclusive rank
      asg_p[i] = p;
      const bool valid = (p < CAP);
      asg_w[i] = valid ? ew[i] : 0.0f;
      if (valid) slot_token[e * CAP + p] = i >> 1;  // i / TOPK
    }
    running += total;
    __syncthreads();
  }
}

// ---------------- gather + cast to bf16 ----------------
__global__ void gather_kernel(const float* __restrict__ x,
                              const int* __restrict__ slot_token,
                              __bf16* __restrict__ Xg) {
  const int s   = blockIdx.x;
  const int tok = slot_token[s];
  const int idx = threadIdx.x * 4;
  bf16x4 o;
  if (tok >= 0) {
    const float4 v = *(const float4*)&x[(size_t)tok * HS + idx];
    o[0] = (__bf16)v.x; o[1] = (__bf16)v.y; o[2] = (__bf16)v.z; o[3] = (__bf16)v.w;
  } else {
    o[0] = (__bf16)0.f; o[1] = (__bf16)0.f; o[2] = (__bf16)0.f; o[3] = (__bf16)0.f;
  }
  *(bf16x4*)&Xg[(size_t)s * HS + idx] = o;
}

// ---------------- transpose + cast: [R][C] f32 -> [C][R] bf16 per expert ----
template<int R, int C>
__global__ void transpose_cast_kernel(const float* __restrict__ in,
                                      __bf16* __restrict__ out) {
  const int e = blockIdx.z;
  const float* in_e  = in  + (size_t)e * R * C;
  __bf16*      out_e = out + (size_t)e * R * C;
  const int c0 = blockIdx.x * 64;
  const int r0 = blockIdx.y * 64;
  __shared__ float tile[64][65];
  const int tid = threadIdx.x;
  const int lc = tid & 15, tr = tid >> 4;
  #pragma unroll
  for (int rr = 0; rr < 4; rr++) {
    const int row = rr * 16 + tr;
    const float4 v = *(const float4*)&in_e[(size_t)(r0 + row) * C + c0 + lc * 4];
    tile[row][lc * 4 + 0] = v.x; tile[row][lc * 4 + 1] = v.y;
    tile[row][lc * 4 + 2] = v.z; tile[row][lc * 4 + 3] = v.w;
  }
  __syncthreads();
  const int cb = tid & 7;
  #pragma unroll
  for (int p = 0; p < 2; p++) {
    const int orow = p * 32 + (tid >> 3);
    bf16x8 o;
    #pragma unroll
    for (int j = 0; j < 8; j++) o[j] = (__bf16)tile[cb * 8 + j][orow];
    *(bf16x8*)&out_e[(size_t)(c0 + orow) * R + r0 + cb * 8] = o;
  }
}

// ---------------- gelu (tanh approx, matches jax.nn.gelu) ----------------
__device__ __forceinline__ float gelu_tanh(float v) {
  const float u = 0.7978845608028654f * (v + 0.044715f * v * v * v);
  const float t = 1.0f - 2.0f / (__expf(2.0f * u) + 1.0f);
  return 0.5f * v * (1.0f + t);
}

// ------- grouped GEMM: 256x256 tile, BK=32, 4-ring LDS, frag pipelining ---
// A: [NE*CAP][K] bf16 row-major, B: [NE][N][K] bf16 (B^T), C: [NE*CAP][N] bf16
// 512 threads = 8 waves (2M x 4N), per-wave output 128x64.
// DATAFLOW FIX vs rounds 0-2 (which all serialized LDS-read drain then MFMA
// drain inside each tile, ~30% MfmaUtil): fragments are DOUBLE-BUFFERED in
// registers across K-tiles. At iter t: issue ds_reads(t) [B + A-low into the
// alternate reg set; A-high of tile t-1 read late from its still-intact LDS
// buffer], then run MFMA(t-1) on the previous reg set. The ~1150cy LDS drain
// of reads(t) overlaps the ~1240cy MFMA drain of tile t-1.
// Ring of 4 LDS buffers, prefetch depth 2: the buffer staged at iter t was
// last READ at iter t-2 and those reads completed behind the iter t-1 lgkm
// waits, which precede every wave's arrival at BAR(t) -> race-free.
// Counted vmcnt(4) at every boundary (retires exactly tile t's 4 staging
// issues; tiles t+1's stay in flight); vmcnt(0) only at the final tile.
// sched_barrier(0) pins {reads, stage} ahead of the MFMA cluster so the
// compiler cannot sink loads whose consumers are an iteration away.
// T2 swizzle (verified: SQ_LDS_BANK_CONFLICT == 0) unchanged.
template<int DO_GELU, int MT_, int NT_>
__global__ __launch_bounds__(512, 2)
void gemm256_kernel(const __bf16* __restrict__ A,
                    const __bf16* __restrict__ B,
                    __bf16* __restrict__ C,
                    int N, int K) {
  const int bid = blockIdx.x;
  const int e   = bid & 7;          // expert -> XCD pinning
  const int g   = bid >> 3;
  const int s   = g >> 4;           // 4x4 super-tiles for L2 locality
  const int r   = g & 15;
  const int sm  = s % (MT_ / 4);
  const int sn  = s / (MT_ / 4);
  const int m0  = (sm * 4 + (r >> 2)) * 256;
  const int n0  = (sn * 4 + (r & 3)) * 256;

  const int tid  = threadIdx.x;
  const int lane = tid & 63;
  const int w    = tid >> 6;        // 0..7
  const int wm   = w >> 2;          // 0..1
  const int wn   = w & 3;           // 0..3

  __shared__ __align__(16) __bf16 ldsA[4][256 * 32];   // 4 x 16 KB
  __shared__ __align__(16) __bf16 ldsB[4][256 * 32];   // 4 x 16 KB

  const size_t Abase = ((size_t)e * CAP + m0) * (size_t)K;
  const size_t Bbase = (size_t)e * N * (size_t)K + (size_t)n0 * K;

  // ---- staging addressing (per lane) ----
  const int srow = w * 16 + (lane >> 2);
  const int scb  = (((lane & 3) ^ ((lane >> 3) & 3)) << 3);  // elems
  const __bf16* gA = A + Abase + (size_t)srow * K + scb;
  const __bf16* gB = B + Bbase + (size_t)srow * K + scb;
  const int ldst = w * 512;   // wave-uniform elem offset within an 8KB issue

  // ---- read addressing (per lane), element offsets, swizzled ----
  const int rA0  = wm * 128 + (lane & 15);
  const int rB0  = wn * 64  + (lane & 15);
  const int aoff = rA0 * 32 + ((((lane >> 4) ^ ((rA0 >> 1) & 3))) << 3);
  const int boff = rB0 * 32 + ((((lane >> 4) ^ ((rB0 >> 1) & 3))) << 3);

  f32x4 acc[8][4] = {};

  const int NKT = K >> 5;   // K-tiles of 32

#define STAGE(co, kt) do {                                                \
    const __bf16* _ga = gA + (size_t)(kt) * 32;                           \
    const __bf16* _gb = gB + (size_t)(kt) * 32;                           \
    gload_lds16(_ga,                   &ldsA[(co)][ldst]);                \
    gload_lds16(_ga + (size_t)128 * K, &ldsA[(co)][4096 + ldst]);         \
    gload_lds16(_gb,                   &ldsB[(co)][ldst]);                \
    gload_lds16(_gb + (size_t)128 * K, &ldsB[(co)][4096 + ldst]);         \
  } while (0)

#define READ_BL(bq, al, co) do {                                          \
    const __bf16* _pb = &ldsB[(co)][0];                                   \
    const __bf16* _pa = &ldsA[(co)][0];                                   \
    _Pragma("unroll") for (int _i = 0; _i < 4; ++_i)                      \
      bq[_i] = *(const bf16x8*)&_pb[boff + _i * 512];                     \
    _Pragma("unroll") for (int _i = 0; _i < 4; ++_i)                      \
      al[_i] = *(const bf16x8*)&_pa[aoff + _i * 512];                     \
  } while (0)

#define READ_H(ah, co) do {                                               \
    const __bf16* _pa = &ldsA[(co)][0];                                   \
    _Pragma("unroll") for (int _i = 0; _i < 4; ++_i)                      \
      ah[_i] = *(const bf16x8*)&_pa[aoff + 2048 + _i * 512];              \
  } while (0)

#define MFMA_L(al, bq) do {                                               \
    _Pragma("unroll") for (int _m = 0; _m < 4; ++_m)                      \
      _Pragma("unroll") for (int _n = 0; _n < 4; ++_n)                    \
        acc[_m][_n] = __builtin_amdgcn_mfma_f32_16x16x32_bf16(            \
            al[_m], bq[_n], acc[_m][_n], 0, 0, 0);                        \
  } while (0)

#define MFMA_H(ah, bq) do {                                               \
    _Pragma("unroll") for (int _m = 0; _m < 4; ++_m)                      \
      _Pragma("unroll") for (int _n = 0; _n < 4; ++_n)                    \
        acc[4 + _m][_n] = __builtin_amdgcn_mfma_f32_16x16x32_bf16(        \
            ah[_m], bq[_n], acc[4 + _m][_n], 0, 0, 0);                    \
  } while (0)

  bf16x8 bA[4], lA[4], bB[4], lB[4], hP[4];

  // prologue: stage K-tiles 0,1 (8 vmem issues per wave)
  STAGE(0, 0); STAGE(1, 1);

  // iter 0: load frag set A from tile 0; no MFMA yet
  asm volatile("s_waitcnt vmcnt(4)" ::: "memory");   // retire tile 0's 4
  __builtin_amdgcn_s_barrier();
  asm volatile("" ::: "memory");
  READ_BL(bA, lA, 0);
  STAGE(2, 2);
  __builtin_amdgcn_sched_barrier(0);

  for (int t = 1; t <= NKT - 3; t += 2) {
    // ---- iter t (odd): read set B (tile t) + hP (tile t-1); MFMA tile t-1
    asm volatile("s_waitcnt vmcnt(4)" ::: "memory");
    __builtin_amdgcn_s_barrier();
    asm volatile("" ::: "memory");
    READ_BL(bB, lB, t & 3);
    READ_H(hP, (t - 1) & 3);
    STAGE((t + 2) & 3, t + 2);
    __builtin_amdgcn_sched_barrier(0);
    __builtin_amdgcn_s_setprio(1);
    MFMA_L(lA, bA);          // operands ready since last iter: fires at once
    MFMA_H(hP, bA);          // hP latency hidden under MFMA_L
    __builtin_amdgcn_s_setprio(0);

    // ---- iter t+1 (even): read set A (tile t+1) + hP (tile t); MFMA tile t
    asm volatile("s_waitcnt vmcnt(4)" ::: "memory");
    __builtin_amdgcn_s_barrier();
    asm volatile("" ::: "memory");
    READ_BL(bA, lA, (t + 1) & 3);
    READ_H(hP, t & 3);
    if (t + 3 < NKT) STAGE((t + 3) & 3, t + 3);
    __builtin_amdgcn_sched_barrier(0);
    __builtin_amdgcn_s_setprio(1);
    MFMA_L(lB, bB);
    MFMA_H(hP, bB);
    __builtin_amdgcn_s_setprio(0);
  }

  // final iter t = NKT-1 (odd): drain staging fully
  asm volatile("s_waitcnt vmcnt(0)" ::: "memory");
  __builtin_amdgcn_s_barrier();
  asm volatile("" ::: "memory");
  READ_BL(bB, lB, (NKT - 1) & 3);
  READ_H(hP, (NKT - 2) & 3);
  __builtin_amdgcn_sched_barrier(0);
  __builtin_amdgcn_s_setprio(1);
  MFMA_L(lA, bA);
  MFMA_H(hP, bA);
  // last tile's MFMA (buffers untouched; no barrier needed)
  READ_H(hP, (NKT - 1) & 3);
  MFMA_L(lB, bB);
  MFMA_H(hP, bB);
  __builtin_amdgcn_s_setprio(0);

#undef STAGE
#undef READ_BL
#undef READ_H
#undef MFMA_L
#undef MFMA_H

  // ---- epilogue: D row=(lane>>4)*4+rr (m), col=lane&15 (n) ----
  const int crow = (lane >> 4) * 4;
  const int ccol = lane & 15;
  const size_t Crow0 = (size_t)e * CAP + m0 + wm * 128;
  #pragma unroll
  for (int mi = 0; mi < 8; ++mi) {
    #pragma unroll
    for (int ni = 0; ni < 4; ++ni) {
      const f32x4 d = acc[mi][ni];
      const int col = n0 + wn * 64 + ni * 16 + ccol;
      #pragma unroll
      for (int rr = 0; rr < 4; ++rr) {
        float v = d[rr];
        if (DO_GELU) v = gelu_tanh(v);
        C[(Crow0 + mi * 16 + crow + rr) * (size_t)N + col] = (__bf16)v;
      }
    }
  }
}

// ---------------- combine: y = bias + sum_k w * Out[slot] ----------------
__global__ void combine_kernel(const __bf16* __restrict__ Out,
                               const int* __restrict__ te,
                               const int* __restrict__ asg_p,
                               const float* __restrict__ asg_w,
                               const float* __restrict__ bias,
                               float* __restrict__ y) {
  const int t   = blockIdx.x;
  const int idx = threadIdx.x * 4;
  f32x4 acc = *(const f32x4*)&bias[idx];
  #pragma unroll
  for (int j = 0; j < TOPK; j++) {
    const int i = t * TOPK + j;
    const float wgt = asg_w[i];
    if (wgt != 0.0f) {
      const int slot = te[i] * CAP + asg_p[i];
      const bf16x4 o = *(const bf16x4*)&Out[(size_t)slot * HS + idx];
      acc[0] += wgt * (float)o[0];
      acc[1] += wgt * (float)o[1];
      acc[2] += wgt * (float)o[2];
      acc[3] += wgt * (float)o[3];
    }
  }
  *(f32x4*)&y[(size_t)t * HS + idx] = acc;
}

// ---------------- workspace layout (bytes) ----------------
static constexpr size_t OFF_SLOT = 0;                          //  64 KB int
static constexpr size_t OFF_ASGP = 65536;                      //  64 KB int
static constexpr size_t OFF_ASGW = 131072;                     //  64 KB f32
static constexpr size_t OFF_XG   = 196608;                     //  32 MB bf16 [NE*CAP][HS]
static constexpr size_t OFF_W1T  = OFF_XG  + (size_t)TK * HS * 2;        // 64 MB bf16 [NE][FFN][HS]
static constexpr size_t OFF_W2T  = OFF_W1T + (size_t)NE * HS * FFN * 2;  // 64 MB bf16 [NE][HS][FFN]
static constexpr size_t OFF_H    = OFF_W2T + (size_t)NE * HS * FFN * 2;  // 128 MB bf16 [NE*CAP][FFN]
static constexpr size_t OFF_OUT  = OFF_H   + (size_t)NE * CAP * FFN * 2; // 32 MB bf16 [NE*CAP][HS]

extern "C" void kernel_launch(void* const* d_in, const int* in_sizes, int n_in,
                              void* d_out, int out_size, void* d_ws, size_t ws_size,
                              hipStream_t stream) {
  const float* x    = (const float*)d_in[0];
  const float* ew   = (const float*)d_in[1];
  const float* w1   = (const float*)d_in[2];
  const float* w2   = (const float*)d_in[3];
  const float* bias = (const float*)d_in[4];
  const int*   te   = (const int*)d_in[5];
  float* y = (float*)d_out;

  char* ws = (char*)d_ws;
  int*    slot_token = (int*)(ws + OFF_SLOT);
  int*    asg_p      = (int*)(ws + OFF_ASGP);
  float*  asg_w      = (float*)(ws + OFF_ASGW);
  __bf16* Xg         = (__bf16*)(ws + OFF_XG);
  __bf16* W1t        = (__bf16*)(ws + OFF_W1T);
  __bf16* W2t        = (__bf16*)(ws + OFF_W2T);
  __bf16* H          = (__bf16*)(ws + OFF_H);
  __bf16* Out        = (__bf16*)(ws + OFF_OUT);

  // 1. slot_token = -1
  hipMemsetAsync(slot_token, 0xFF, (size_t)NE * CAP * sizeof(int), stream);

  // 2. routing (stable ranks)
  route_kernel<<<NE, 1024, 0, stream>>>(te, ew, asg_p, asg_w, slot_token);

  // 3. weight transpose+cast
  transpose_cast_kernel<HS, FFN><<<dim3(FFN / 64, HS / 64, NE), 256, 0, stream>>>(w1, W1t);
  transpose_cast_kernel<FFN, HS><<<dim3(HS / 64, FFN / 64, NE), 256, 0, stream>>>(w2, W2t);

  // 4. gather tokens into expert bins (bf16)
  gather_kernel<<<NE * CAP, 256, 0, stream>>>(x, slot_token, Xg);

  // 5. H = gelu(Xg @ w1)   (M=CAP, N=FFN, K=HS)   8 m-tiles, 16 n-tiles
  gemm256_kernel<1, 8, 16><<<NE * 8 * 16, 512, 0, stream>>>(Xg, W1t, H, FFN, HS);

  // 6. Out = H @ w2        (M=CAP, N=HS, K=FFN)   8 m-tiles, 4 n-tiles
  gemm256_kernel<0, 8, 4><<<NE * 8 * 4, 512, 0, stream>>>(H, W2t, Out, HS, FFN);

  // 7. combine back to tokens
  combine_kernel<<<NT, 256, 0, stream>>>(Out, te, asg_p, asg_w, bias, y);
}